// Round 8
// baseline (499.631 us; speedup 1.0000x reference)
//
#include <hip/hip_runtime.h>
#include <stdint.h>

#define HH 1024
#define WW 2048
#define HWN (HH*WW)          // 2097152
#define BIGL HWN             // 'no cluster' sentinel
#define NSLOTS 26
#define MINCL 30
#define THREADS 256
#define MAXCAND 70000        // >= HWN/30 + 1
#define HSZ 512              // run-aggregation hash entries (256-px strip)
#define TH 16                // tile height
#define TPX (TH*64)          // 1024 px per tile
#define NTIL ((HH/TH)*(WW/64))   // 64*32 = 2048 tiles
#define MTHREADS 128         // k_merge block size
#define NBORDER (HWN/THREADS)    // 8192 border_stats blocks
#define OV4 (NSLOTS*HWN/4)   // out vi4 count: 13631488
#define OV4B (OV4/NTIL)      // 6656 vi4 per k_local block
#define KREG 32              // register-cached selection keys per thread

typedef int vi4 __attribute__((ext_vector_type(4)));
typedef unsigned long long u64;

// ---------------- global union-find (lock-free, min-root) ----------------
__device__ __forceinline__ int uf_load(int* p, int i) {
    return __hip_atomic_load(&p[i], __ATOMIC_RELAXED, __HIP_MEMORY_SCOPE_AGENT);
}
__device__ __forceinline__ void uf_store(int* p, int i, int v) {
    __hip_atomic_store(&p[i], v, __ATOMIC_RELAXED, __HIP_MEMORY_SCOPE_AGENT);
}
__device__ int uf_find(int* parent, int x) {
    int p = uf_load(parent, x);
    while (p != x) {
        int gp = uf_load(parent, p);
        if (gp != p) uf_store(parent, x, gp);   // path halving (benign race)
        x = p; p = gp;
    }
    return p;
}
__device__ void uf_union(int* parent, int a, int b) {
    int ra = uf_find(parent, a);
    int rb = uf_find(parent, b);
    while (ra != rb) {
        if (ra > rb) { int t = ra; ra = rb; rb = t; }   // hook larger under smaller
        int old = atomicCAS(&parent[rb], rb, ra);
        if (old == rb) return;
        rb = uf_find(parent, old);
        ra = uf_find(parent, ra);
    }
}

// ---------------- LDS union-find (block-local, min-root) ----------------
__device__ __forceinline__ int l_load(int* p, int i) {
    return __hip_atomic_load(&p[i], __ATOMIC_RELAXED, __HIP_MEMORY_SCOPE_WORKGROUP);
}
__device__ __forceinline__ void l_store(int* p, int i, int v) {
    __hip_atomic_store(&p[i], v, __ATOMIC_RELAXED, __HIP_MEMORY_SCOPE_WORKGROUP);
}
__device__ int l_find(int* lp, int x) {
    int p = l_load(lp, x);
    while (p != x) {
        int gp = l_load(lp, p);
        if (gp != p) l_store(lp, x, gp);
        x = p; p = gp;
    }
    return p;
}
__device__ void l_union(int* lp, int a, int b) {
    int ra = l_find(lp, a);
    int rb = l_find(lp, b);
    while (ra != rb) {
        if (ra > rb) { int t = ra; ra = rb; rb = t; }
        int old = atomicCAS(&lp[rb], rb, ra);
        if (old == rb) return;
        rb = l_find(lp, old);
        ra = l_find(lp, ra);
    }
}

// ---------------- fused init + per-tile CC + ws/out zeroing ----------------
// 16x64 tiles, 256 threads (4 waves), 2048 blocks -> 8 blocks/CU.
// Also NT-zeros the 218 MB output buffer (pure write BW, proven non-hideable
// but location-neutral — keeping it here lets k_output write only sparse 1s).
// parent[] is self-describing: -1 for non-core, global tile-root for core.
__global__ __launch_bounds__(THREADS) void k_local(const float* __restrict__ mask,
                                                   uint8_t* __restrict__ flags,
                                                   int* __restrict__ parent,
                                                   int* __restrict__ sizes,
                                                   unsigned* __restrict__ colsum,
                                                   signed char* __restrict__ chan,
                                                   int* __restrict__ counter,
                                                   int* __restrict__ out) {
    __shared__ uint8_t lact[18 * 72];   // halo active map, row stride 72
    __shared__ uint8_t lc8[TPX];
    __shared__ int lp[TPX];
    const int tid = threadIdx.x;
    const int lane = tid & 63;
    int tile_x = blockIdx.x & 31, tile_y = blockIdx.x >> 5;
    int r0 = tile_y << 4, c0 = tile_x << 6;

    {   // zero this block's slice of out (26 vi4/thread, NT)
        vi4* o4 = (vi4*)out + (size_t)blockIdx.x * OV4B;
        #pragma unroll
        for (int t = 0; t < OV4B / THREADS; ++t)
            __builtin_nontemporal_store((vi4)0, o4 + t * THREADS + tid);
    }
    {   // zero this block's 1/2048 slice of sizes/colsum/chan (+counter once)
        int base = blockIdx.x * TPX;                 // 1024 elements
        ((vi4*)(sizes + base))[tid & 255] = (vi4)0;  // 256 vi4
        ((vi4*)(colsum + base))[tid & 255] = (vi4)0; // 256 vi4 (u32)
        if (tid < 64) ((vi4*)(chan + base))[tid] = (vi4)(-1);
        if (blockIdx.x == 0 && tid == 0) { counter[0] = 0; counter[1] = 0; }
    }

    {   // body rows: 16 rows x 16 float4, coalesced, one pass
        int lr = tid >> 4, q = tid & 15;
        const float4* src = (const float4*)(mask + (size_t)(r0 + lr) * WW + c0);
        float4 v = src[q];
        uint8_t* dst = &lact[(lr + 1) * 72 + (q * 4 + 1)];
        dst[0] = v.x > 0.1f; dst[1] = v.y > 0.1f;
        dst[2] = v.z > 0.1f; dst[3] = v.w > 0.1f;
    }
    if (tid < 32) {          // halo top/bottom rows (cols 1..64)
        int q = tid & 15;
        bool top = tid < 16;
        int gr = top ? r0 - 1 : r0 + TH;
        int yy = top ? 0 : TH + 1;
        uint8_t* dst = &lact[yy * 72 + (q * 4 + 1)];
        if ((unsigned)gr < HH) {
            const float4* src = (const float4*)(mask + (size_t)gr * WW + c0);
            float4 v = src[q];
            dst[0] = v.x > 0.1f; dst[1] = v.y > 0.1f;
            dst[2] = v.z > 0.1f; dst[3] = v.w > 0.1f;
        } else {
            dst[0] = 0; dst[1] = 0; dst[2] = 0; dst[3] = 0;
        }
    } else if (tid >= 64 && tid < 64 + 36) {    // halo cols incl corners
        int ln = tid - 64;                      // 0..35
        int side = ln >= 18;                    // 0=left(c0-1), 1=right(c0+64)
        int yy = side ? ln - 18 : ln;           // 0..17
        int gr = r0 - 1 + yy;
        int gc = side ? c0 + 64 : c0 - 1;
        bool a = false;
        if ((unsigned)gr < HH && (unsigned)gc < WW) a = mask[(size_t)gr * WW + gc] > 0.1f;
        lact[yy * 72 + (side ? 65 : 0)] = a ? 1 : 0;
    }
    __syncthreads();
    // core flags + run-head lp init (one wave == one tile row per pass)
    #pragma unroll
    for (int pass = 0; pass < 4; ++pass) {
        int li = tid + pass * THREADS;
        int lr = li >> 6, lc = li & 63;
        int b = (lr + 1) * 72 + (lc + 1);
        int a = lact[b];
        int cnt = lact[b - 73] + lact[b - 72] + lact[b - 71]
                + lact[b - 1]  + a           + lact[b + 1]
                + lact[b + 71] + lact[b + 72] + lact[b + 73];
        bool core = a && (cnt >= 4);                    // MIN_SAMPLES=4 incl self
        lc8[li] = (uint8_t)(a | (core ? 2 : 0));
        u64 bc = __ballot(core);
        u64 st = bc & ~(bc << 1);                       // run starts
        int hl = 63 - __clzll(st & ((2ull << lane) - 1));  // valid iff core
        lp[li] = core ? ((li & ~63) | hl) : li;
    }
    __syncthreads();
    if (tid < 64) {   // flags -> global, 16B per thread
        int row = tid >> 2, chunk = tid & 3;
        ((uint4*)(flags + (size_t)(r0 + row) * WW + c0))[chunk] =
            ((const uint4*)lc8)[row * 4 + chunk];
    }
    // vertical/diagonal unions between run heads, one per overlap segment
    #pragma unroll
    for (int pass = 0; pass < 4; ++pass) {
        int li = tid + pass * THREADS;
        int row = li >> 6;
        if (row == 0) continue;                         // wave-uniform
        bool core  = (lc8[li] & 2) != 0;
        bool ncore = (lc8[li - 64] & 2) != 0;
        u64 bc = __ballot(core);
        u64 nb = __ballot(ncore);
        if (!bc || !nb) continue;                       // wave-uniform
        u64 sst = bc & ~(bc << 1);
        u64 nst = nb & ~(nb << 1);
        if (core) {
            int myhead = (li & ~63) | (63 - __clzll(sst & ((2ull << lane) - 1)));
            int nrow0 = (li - 64) & ~63;
            if (ncore) {
                bool prevpair = lane > 0 && ((bc >> (lane - 1)) & 1)
                                         && ((nb >> (lane - 1)) & 1);
                bool newseg = !prevpair || ((sst >> lane) & 1) || ((nst >> lane) & 1);
                if (newseg) {
                    int nhead = nrow0 | (63 - __clzll(nst & ((2ull << lane) - 1)));
                    l_union(lp, myhead, nhead);
                }
            } else {
                bool wcore  = lane > 0 && ((bc >> (lane - 1)) & 1);
                bool nwcore = lane > 0 && ((nb >> (lane - 1)) & 1);
                if (!wcore && nwcore) {
                    int nhead = nrow0 | (63 - __clzll(nst & ((1ull << lane) - 1)));
                    l_union(lp, myhead, nhead);
                }
                bool ecore  = lane < 63 && ((bc >> (lane + 1)) & 1);
                bool necore = lane < 63 && ((nb >> (lane + 1)) & 1);
                if (!ecore && necore) {
                    int nhead = nrow0 | (63 - __clzll(nst & ((4ull << lane) - 1)));
                    l_union(lp, myhead, nhead);
                }
            }
        }
    }
    __syncthreads();
    // write parent for ALL pixels: core -> global root, non-core -> -1
    #pragma unroll
    for (int pass = 0; pass < 4; ++pass) {
        int li = tid + pass * THREADS;
        int v = -1;
        if (lc8[li] & 2) {
            int root = li, p;
            while ((p = lp[root]) != root) root = p;   // lp stable after barrier
            v = (r0 + (root >> 6)) * WW + c0 + (root & 63);
        }
        int gi = (r0 + (li >> 6)) * WW + c0 + (li & 63);
        parent[gi] = v;
    }
}

// union only tile-crossing edges (16x64 tiles)
__global__ __launch_bounds__(MTHREADS) void k_merge(const uint8_t* __restrict__ flags,
                                                    int* __restrict__ parent) {
    int tile_x = blockIdx.x & 31, tile_y = blockIdx.x >> 5;
    int r0 = tile_y << 4, c0 = tile_x << 6;
    int t = threadIdx.x;
    int lane = t & 63;

    if (t < 64) {                                    // top row, lr=0, lc=t
        int r = r0, c = c0 + t, i = r * WW + c;
        bool selfC = (flags[i] & 2) != 0;
        bool nC = false, nwC = false, neC = false;
        if (selfC && r > 0) {
            nC  = (flags[i - WW] & 2) != 0;
            nwC = (c > 0)      && (flags[i - WW - 1] & 2);
            neC = (c < WW - 1) && (flags[i - WW + 1] & 2);
        }
        int did = 0, ra = -1, rb = -1;
        if (selfC && r > 0 && nC) { ra = uf_find(parent, i); rb = uf_find(parent, i - WW); did = 1; }
        int pra = __shfl_up(ra, 1), prb = __shfl_up(rb, 1), pdid = __shfl_up(did, 1);
        bool head = (lane == 0) || !pdid || pra != ra || prb != rb;
        if (did && head) uf_union(parent, ra, rb);
        if (selfC && r > 0) {
            if (t == 0) {
                if (nwC) uf_union(parent, i, i - WW - 1);          // diag tile
                if (!nC && neC) uf_union(parent, i, i - WW + 1);
            } else if (t == 63) {
                if (!nC && nwC) uf_union(parent, i, i - WW - 1);
                if (neC) {
                    bool eC = (c < WW - 1) && (flags[i + 1] & 2);
                    if (!eC) uf_union(parent, i, i - WW + 1);
                }
            } else if (!nC) {
                if (nwC) uf_union(parent, i, i - WW - 1);
                if (neC) uf_union(parent, i, i - WW + 1);
            }
        }
        if (t == 0 && selfC && c > 0 && (flags[i - 1] & 2))        // corner W edge
            uf_union(parent, i, i - 1);
    } else if (t < 64 + TH - 1) {                    // left col, lr=1..15, lc=0
        int lr = t - 63;
        int r = r0 + lr, c = c0, i = r * WW + c;
        bool selfC = (flags[i] & 2) != 0;
        bool wC = false, nwC = false;
        if (selfC && c > 0) {
            wC  = (flags[i - 1] & 2) != 0;
            nwC = (flags[i - WW - 1] & 2) != 0;
        }
        int did = 0, ra = -1, rb = -1;
        if (selfC && wC) { ra = uf_find(parent, i); rb = uf_find(parent, i - 1); did = 1; }
        int pra = __shfl_up(ra, 1), prb = __shfl_up(rb, 1), pdid = __shfl_up(did, 1);
        bool head = (lane == 0) || !pdid || pra != ra || prb != rb;
        if (did && head) uf_union(parent, ra, rb);
        if (selfC && !wC && nwC) uf_union(parent, i, i - WW - 1);
    } else if (t < 64 + 2 * (TH - 1)) {              // right col, lr=1..15, lc=63
        int lr = t - (64 + TH - 2);
        int r = r0 + lr, c = c0 + 63, i = r * WW + c;
        bool selfC = (flags[i] & 2) != 0;
        if (selfC && c < WW - 1) {
            bool neC = (flags[i - WW + 1] & 2) != 0;
            bool eC  = (flags[i + 1] & 2) != 0;
            if (neC && !eC) uf_union(parent, i, i - WW + 1);
        }
    }
}

// ---------------- flatten: parent[i] -> final global root ----------------
__global__ __launch_bounds__(THREADS) void k_flatten(int* __restrict__ parent) {
    int i4 = (blockIdx.x * THREADS + threadIdx.x) * 4;
    vi4 v = *((vi4*)(parent + i4));
    vi4 o = v;
    #pragma unroll
    for (int t = 0; t < 4; ++t) {
        int p = v[t];
        if (p >= 0) {
            int q = uf_load(parent, p);
            while (q != p) { p = q; q = uf_load(parent, p); }
            v[t] = p;
        }
    }
    if (v.x != o.x || v.y != o.y || v.z != o.z || v.w != o.w)
        *((vi4*)(parent + i4)) = v;
}

__device__ __forceinline__ u64 wave_min_u64(u64 m) {
    #pragma unroll
    for (int off = 32; off; off >>= 1) {
        u64 o = __shfl_xor(m, off);
        if (o < m) m = o;
    }
    return m;
}

// ---------------- border + stats + fused last-block top-26 ----------------
// parent[] holds FINAL roots. Neighbor probe via 3 coalesced row loads + 6
// wave shuffles. Last finishing block selects top-26 with REGISTER-CACHED
// keys (one gather pass, then 26 rounds of reg-min + block reduce).
__global__ __launch_bounds__(THREADS) void k_border_stats(
        const uint8_t* __restrict__ flags, const int* __restrict__ parent,
        int* __restrict__ labfull, int* __restrict__ sizes,
        unsigned* __restrict__ colsum,
        int* __restrict__ cand, int* __restrict__ counter,
        signed char* __restrict__ chan) {
    __shared__ int s_lab[HSZ];
    __shared__ int s_sz[HSZ];
    __shared__ unsigned s_cs[HSZ];
    const int tid = threadIdx.x;
    for (int t = tid; t < HSZ; t += THREADS) {
        s_lab[t] = -1; s_sz[t] = 0; s_cs[t] = 0;
    }
    __syncthreads();

    const int i = blockIdx.x * THREADS + tid;
    const int f = flags[i];
    const int r = i >> 11, c = i & (WW - 1);
    const int lane = tid & 63;
    const int wv = tid >> 6;

    // 3 coalesced row loads; row predicates are wave-uniform (WW % 64 == 0)
    const int pc = parent[i];
    const int pn = (r > 0)      ? parent[i - WW] : -1;
    const int ps = (r < HH - 1) ? parent[i + WW] : -1;

    // lateral neighbors via shuffles; edge lanes fetch directly
    int wv_c = __shfl_up(pc, 1);
    int wv_n = __shfl_up(pn, 1);
    int wv_s = __shfl_up(ps, 1);
    if (lane == 0) {
        bool ok = (c > 0);
        wv_c = ok ? parent[i - 1] : -1;
        wv_n = (ok && r > 0)      ? parent[i - WW - 1] : -1;
        wv_s = (ok && r < HH - 1) ? parent[i + WW - 1] : -1;
    }
    int ev_c = __shfl_down(pc, 1);
    int ev_n = __shfl_down(pn, 1);
    int ev_s = __shfl_down(ps, 1);
    if (lane == 63) {
        bool ok = (c < WW - 1);
        ev_c = ok ? parent[i + 1] : -1;
        ev_n = (ok && r > 0)      ? parent[i - WW + 1] : -1;
        ev_s = (ok && r < HH - 1) ? parent[i + WW + 1] : -1;
    }

    int lab = BIGL;
    if (f & 2) {
        lab = pc;                                // final root
    } else if (f & 1) {                          // active non-core: min core nbr
        int m = BIGL;
        if (pn   >= 0 && pn   < m) m = pn;
        if (ps   >= 0 && ps   < m) m = ps;
        if (wv_c >= 0 && wv_c < m) m = wv_c;
        if (wv_n >= 0 && wv_n < m) m = wv_n;
        if (wv_s >= 0 && wv_s < m) m = wv_s;
        if (ev_c >= 0 && ev_c < m) m = ev_c;
        if (ev_n >= 0 && ev_n < m) m = ev_n;
        if (ev_s >= 0 && ev_s < m) m = ev_s;
        lab = m;                                 // BIGL if no core neighbor
    }
    labfull[i] = lab;

    // wave-level run aggregation (WW % 64 == 0: wave never crosses a row)
    int labp = __shfl_up(lab, 1);
    bool head = (lane == 0) || (labp != lab);
    u64 hm = __ballot(head);
    if (head && lab < BIGL) {
        u64 rest = (hm >> lane) >> 1;
        int len = rest ? __ffsll(rest) : (64 - lane);
        unsigned csum = (unsigned)(c * len + len * (len - 1) / 2);
        unsigned slot = (((unsigned)lab * 2654435761u) >> 20) & (HSZ - 1);
        for (;;) {
            int old = atomicCAS(&s_lab[slot], -1, lab);
            if (old == -1 || old == lab) {
                atomicAdd(&s_sz[slot], len);
                atomicAdd(&s_cs[slot], csum);
                break;
            }
            slot = (slot + 1) & (HSZ - 1);
        }
    }
    __syncthreads();
    for (int t = tid; t < HSZ; t += THREADS) {
        int lb = s_lab[t];
        if (lb >= 0) {
            int add = s_sz[t];
            int old = atomicAdd(&sizes[lb], add);
            if (old < MINCL && old + add >= MINCL) {   // exactly one block sees this
                int p = atomicAdd(counter, 1);
                __hip_atomic_store(&cand[p], lb, __ATOMIC_RELAXED,
                                   __HIP_MEMORY_SCOPE_AGENT);
            }
            atomicAdd(&colsum[lb], s_cs[t]);
        }
    }

    // ---- last-block top-26 selection (register-cached keys) ----
    __shared__ int lastflag;
    __shared__ u64 bmin[4];
    if (tid == 0) {
        __threadfence();
        lastflag = (atomicAdd(&counter[1], 1) == NBORDER - 1);
    }
    __syncthreads();
    if (!lastflag) return;
    __threadfence();

    const int n = __hip_atomic_load(&counter[0], __ATOMIC_RELAXED,
                                    __HIP_MEMORY_SCOPE_AGENT);
    u64 kk[KREG];
    #pragma unroll
    for (int t = 0; t < KREG; ++t) {
        int j = tid + t * THREADS;
        u64 key = ~0ull;
        if (j < n) {
            int lb = __hip_atomic_load(&cand[j], __ATOMIC_RELAXED,
                                       __HIP_MEMORY_SCOPE_AGENT);
            unsigned cs = __hip_atomic_load(&colsum[lb], __ATOMIC_RELAXED,
                                            __HIP_MEMORY_SCOPE_AGENT);
            int sz = __hip_atomic_load((int*)&sizes[lb], __ATOMIC_RELAXED,
                                       __HIP_MEMORY_SCOPE_AGENT);
            float mean = (float)cs / (float)sz;
            key = ((u64)__float_as_uint(mean) << 32) | (unsigned)lb;
        }
        kk[t] = key;
    }
    const bool ovf = n > KREG * THREADS;          // rare overflow path
    u64 prev = 0;
    for (int k = 0; k < NSLOTS; ++k) {
        u64 best = ~0ull;
        #pragma unroll
        for (int t = 0; t < KREG; ++t) {
            u64 key = kk[t];
            if ((k == 0 || key > prev) && key < best) best = key;
        }
        if (ovf) {
            for (int j = KREG * THREADS + tid; j < n; j += THREADS) {
                int lb = __hip_atomic_load(&cand[j], __ATOMIC_RELAXED,
                                           __HIP_MEMORY_SCOPE_AGENT);
                unsigned cs = __hip_atomic_load(&colsum[lb], __ATOMIC_RELAXED,
                                                __HIP_MEMORY_SCOPE_AGENT);
                int sz = __hip_atomic_load((int*)&sizes[lb], __ATOMIC_RELAXED,
                                           __HIP_MEMORY_SCOPE_AGENT);
                float mean = (float)cs / (float)sz;
                u64 key = ((u64)__float_as_uint(mean) << 32) | (unsigned)lb;
                if ((k == 0 || key > prev) && key < best) best = key;
            }
        }
        best = wave_min_u64(best);
        if (lane == 0) bmin[wv] = best;
        __syncthreads();
        u64 m = bmin[0];
        if (bmin[1] < m) m = bmin[1];
        if (bmin[2] < m) m = bmin[2];
        if (bmin[3] < m) m = bmin[3];
        if (m == ~0ull) break;                        // uniform across block
        if (tid == 0) chan[(unsigned)(m & 0xFFFFFFFFull)] = (signed char)k;
        prev = m;
        __syncthreads();
    }
}

// sparse one-hot output: out[] pre-zeroed by k_local; write only the 1s.
__global__ __launch_bounds__(THREADS) void k_output(const int* __restrict__ labfull,
                                                    const signed char* __restrict__ chan,
                                                    int* __restrict__ out) {
    int i4 = (blockIdx.x * THREADS + threadIdx.x) * 4;
    vi4 lv = __builtin_nontemporal_load((const vi4*)(labfull + i4));
    #pragma unroll
    for (int t = 0; t < 4; ++t) {
        int lab = lv[t];
        if (lab < BIGL) {
            int ch = chan[lab];
            if (ch >= 0)
                __builtin_nontemporal_store(1, out + (size_t)ch * HWN + i4 + t);
        }
    }
}

extern "C" void kernel_launch(void* const* d_in, const int* in_sizes, int n_in,
                              void* d_out, int out_size, void* d_ws, size_t ws_size,
                              hipStream_t stream) {
    const float* mask = (const float*)d_in[0];
    int* out = (int*)d_out;

    char* w = (char*)d_ws;
    int* parent                 = (int*)(w);                          //  8 MB
    int* labfull                = (int*)(w + (size_t)HWN * 4);        //  8 MB
    int* sizes                  = (int*)(w + (size_t)HWN * 8);        //  8 MB
    unsigned* colsum            = (unsigned*)(w + (size_t)HWN * 12);  //  8 MB (u32)
    uint8_t* flags              = (uint8_t*)(w + (size_t)HWN * 16);   //  2 MB
    signed char* chan           = (signed char*)(w + (size_t)HWN * 17); // 2 MB
    int* cand                   = (int*)(w + (size_t)HWN * 18);       // 280 KB
    int* counter                = (int*)(w + (size_t)HWN * 18 + MAXCAND * 4);  // [0]=n,[1]=done

    // no memsets: k_local zeros sizes/colsum/chan/counter and the out buffer
    k_local       <<<NTIL, THREADS, 0, stream>>>(mask, flags, parent,
                                                 sizes, colsum, chan, counter, out);
    k_merge       <<<NTIL, MTHREADS, 0, stream>>>(flags, parent);
    k_flatten     <<<HWN / (4 * THREADS), THREADS, 0, stream>>>(parent);
    k_border_stats<<<NBORDER, THREADS, 0, stream>>>(flags, parent, labfull, sizes,
                                                    colsum, cand, counter, chan);
    k_output      <<<HWN / (4 * THREADS), THREADS, 0, stream>>>(labfull, chan, out);
}

// Round 9
// 368.738 us; speedup vs baseline: 1.3550x; 1.3550x over previous
//
#include <hip/hip_runtime.h>
#include <stdint.h>

#define HH 1024
#define WW 2048
#define HWN (HH*WW)          // 2097152
#define BIGL HWN             // 'no cluster' sentinel
#define NSLOTS 26
#define MINCL 30
#define THREADS 256
#define MAXCAND 70000        // >= HWN/30 + 1
#define HSZ 512              // run-aggregation hash entries (256-px strip)
#define TH 16                // tile height
#define TPX (TH*64)          // 1024 px per tile
#define NTIL ((HH/TH)*(WW/64))   // 64*32 = 2048 tiles
#define MTHREADS 128         // k_merge block size
#define NBORDER (HWN/THREADS)    // 8192 border_stats blocks
#define NB 128               // selection blocks
#define OV4 (NSLOTS*HWN/4)   // out vi4 count: 13631488
#define OV4B (OV4/NTIL)      // 6656 vi4 per k_local block

typedef int vi4 __attribute__((ext_vector_type(4)));
typedef unsigned long long u64;

// ---------------- global union-find (lock-free, min-root) ----------------
__device__ __forceinline__ int uf_load(int* p, int i) {
    return __hip_atomic_load(&p[i], __ATOMIC_RELAXED, __HIP_MEMORY_SCOPE_AGENT);
}
__device__ __forceinline__ void uf_store(int* p, int i, int v) {
    __hip_atomic_store(&p[i], v, __ATOMIC_RELAXED, __HIP_MEMORY_SCOPE_AGENT);
}
__device__ int uf_find(int* parent, int x) {
    int p = uf_load(parent, x);
    while (p != x) {
        int gp = uf_load(parent, p);
        if (gp != p) uf_store(parent, x, gp);   // path halving (benign race)
        x = p; p = gp;
    }
    return p;
}
__device__ void uf_union(int* parent, int a, int b) {
    int ra = uf_find(parent, a);
    int rb = uf_find(parent, b);
    while (ra != rb) {
        if (ra > rb) { int t = ra; ra = rb; rb = t; }   // hook larger under smaller
        int old = atomicCAS(&parent[rb], rb, ra);
        if (old == rb) return;
        rb = uf_find(parent, old);
        ra = uf_find(parent, ra);
    }
}

// ---------------- LDS union-find (block-local, min-root) ----------------
__device__ __forceinline__ int l_load(int* p, int i) {
    return __hip_atomic_load(&p[i], __ATOMIC_RELAXED, __HIP_MEMORY_SCOPE_WORKGROUP);
}
__device__ __forceinline__ void l_store(int* p, int i, int v) {
    __hip_atomic_store(&p[i], v, __ATOMIC_RELAXED, __HIP_MEMORY_SCOPE_WORKGROUP);
}
__device__ int l_find(int* lp, int x) {
    int p = l_load(lp, x);
    while (p != x) {
        int gp = l_load(lp, p);
        if (gp != p) l_store(lp, x, gp);
        x = p; p = gp;
    }
    return p;
}
__device__ void l_union(int* lp, int a, int b) {
    int ra = l_find(lp, a);
    int rb = l_find(lp, b);
    while (ra != rb) {
        if (ra > rb) { int t = ra; ra = rb; rb = t; }
        int old = atomicCAS(&lp[rb], rb, ra);
        if (old == rb) return;
        rb = l_find(lp, old);
        ra = l_find(lp, ra);
    }
}

// ---------------- fused init + per-tile CC + ws/out zeroing ----------------
// 16x64 tiles, 256 threads (4 waves), 2048 blocks -> 8 blocks/CU.
// Also NT-zeros the 218 MB output buffer (location-neutral pure write BW;
// keeping it here lets k_output write only sparse 1s).
// parent[] is self-describing: -1 for non-core, global tile-root for core.
__global__ __launch_bounds__(THREADS) void k_local(const float* __restrict__ mask,
                                                   uint8_t* __restrict__ flags,
                                                   int* __restrict__ parent,
                                                   int* __restrict__ sizes,
                                                   unsigned* __restrict__ colsum,
                                                   signed char* __restrict__ chan,
                                                   int* __restrict__ counter,
                                                   int* __restrict__ out) {
    __shared__ uint8_t lact[18 * 72];   // halo active map, row stride 72
    __shared__ uint8_t lc8[TPX];
    __shared__ int lp[TPX];
    const int tid = threadIdx.x;
    const int lane = tid & 63;
    int tile_x = blockIdx.x & 31, tile_y = blockIdx.x >> 5;
    int r0 = tile_y << 4, c0 = tile_x << 6;

    {   // zero this block's slice of out (26 vi4/thread, NT)
        vi4* o4 = (vi4*)out + (size_t)blockIdx.x * OV4B;
        #pragma unroll
        for (int t = 0; t < OV4B / THREADS; ++t)
            __builtin_nontemporal_store((vi4)0, o4 + t * THREADS + tid);
    }
    {   // zero this block's 1/2048 slice of sizes/colsum/chan (+counter once)
        int base = blockIdx.x * TPX;                 // 1024 elements
        ((vi4*)(sizes + base))[tid & 255] = (vi4)0;  // 256 vi4
        ((vi4*)(colsum + base))[tid & 255] = (vi4)0; // 256 vi4 (u32)
        if (tid < 64) ((vi4*)(chan + base))[tid] = (vi4)(-1);
        if (blockIdx.x == 0 && tid == 0) { counter[0] = 0; counter[1] = 0; }
    }

    {   // body rows: 16 rows x 16 float4, coalesced, one pass
        int lr = tid >> 4, q = tid & 15;
        const float4* src = (const float4*)(mask + (size_t)(r0 + lr) * WW + c0);
        float4 v = src[q];
        uint8_t* dst = &lact[(lr + 1) * 72 + (q * 4 + 1)];
        dst[0] = v.x > 0.1f; dst[1] = v.y > 0.1f;
        dst[2] = v.z > 0.1f; dst[3] = v.w > 0.1f;
    }
    if (tid < 32) {          // halo top/bottom rows (cols 1..64)
        int q = tid & 15;
        bool top = tid < 16;
        int gr = top ? r0 - 1 : r0 + TH;
        int yy = top ? 0 : TH + 1;
        uint8_t* dst = &lact[yy * 72 + (q * 4 + 1)];
        if ((unsigned)gr < HH) {
            const float4* src = (const float4*)(mask + (size_t)gr * WW + c0);
            float4 v = src[q];
            dst[0] = v.x > 0.1f; dst[1] = v.y > 0.1f;
            dst[2] = v.z > 0.1f; dst[3] = v.w > 0.1f;
        } else {
            dst[0] = 0; dst[1] = 0; dst[2] = 0; dst[3] = 0;
        }
    } else if (tid >= 64 && tid < 64 + 36) {    // halo cols incl corners
        int ln = tid - 64;                      // 0..35
        int side = ln >= 18;                    // 0=left(c0-1), 1=right(c0+64)
        int yy = side ? ln - 18 : ln;           // 0..17
        int gr = r0 - 1 + yy;
        int gc = side ? c0 + 64 : c0 - 1;
        bool a = false;
        if ((unsigned)gr < HH && (unsigned)gc < WW) a = mask[(size_t)gr * WW + gc] > 0.1f;
        lact[yy * 72 + (side ? 65 : 0)] = a ? 1 : 0;
    }
    __syncthreads();
    // core flags + run-head lp init (one wave == one tile row per pass)
    #pragma unroll
    for (int pass = 0; pass < 4; ++pass) {
        int li = tid + pass * THREADS;
        int lr = li >> 6, lc = li & 63;
        int b = (lr + 1) * 72 + (lc + 1);
        int a = lact[b];
        int cnt = lact[b - 73] + lact[b - 72] + lact[b - 71]
                + lact[b - 1]  + a           + lact[b + 1]
                + lact[b + 71] + lact[b + 72] + lact[b + 73];
        bool core = a && (cnt >= 4);                    // MIN_SAMPLES=4 incl self
        lc8[li] = (uint8_t)(a | (core ? 2 : 0));
        u64 bc = __ballot(core);
        u64 st = bc & ~(bc << 1);                       // run starts
        int hl = 63 - __clzll(st & ((2ull << lane) - 1));  // valid iff core
        lp[li] = core ? ((li & ~63) | hl) : li;
    }
    __syncthreads();
    if (tid < 64) {   // flags -> global, 16B per thread
        int row = tid >> 2, chunk = tid & 3;
        ((uint4*)(flags + (size_t)(r0 + row) * WW + c0))[chunk] =
            ((const uint4*)lc8)[row * 4 + chunk];
    }
    // vertical/diagonal unions between run heads, one per overlap segment
    #pragma unroll
    for (int pass = 0; pass < 4; ++pass) {
        int li = tid + pass * THREADS;
        int row = li >> 6;
        if (row == 0) continue;                         // wave-uniform
        bool core  = (lc8[li] & 2) != 0;
        bool ncore = (lc8[li - 64] & 2) != 0;
        u64 bc = __ballot(core);
        u64 nb = __ballot(ncore);
        if (!bc || !nb) continue;                       // wave-uniform
        u64 sst = bc & ~(bc << 1);
        u64 nst = nb & ~(nb << 1);
        if (core) {
            int myhead = (li & ~63) | (63 - __clzll(sst & ((2ull << lane) - 1)));
            int nrow0 = (li - 64) & ~63;
            if (ncore) {
                bool prevpair = lane > 0 && ((bc >> (lane - 1)) & 1)
                                         && ((nb >> (lane - 1)) & 1);
                bool newseg = !prevpair || ((sst >> lane) & 1) || ((nst >> lane) & 1);
                if (newseg) {
                    int nhead = nrow0 | (63 - __clzll(nst & ((2ull << lane) - 1)));
                    l_union(lp, myhead, nhead);
                }
            } else {
                bool wcore  = lane > 0 && ((bc >> (lane - 1)) & 1);
                bool nwcore = lane > 0 && ((nb >> (lane - 1)) & 1);
                if (!wcore && nwcore) {
                    int nhead = nrow0 | (63 - __clzll(nst & ((1ull << lane) - 1)));
                    l_union(lp, myhead, nhead);
                }
                bool ecore  = lane < 63 && ((bc >> (lane + 1)) & 1);
                bool necore = lane < 63 && ((nb >> (lane + 1)) & 1);
                if (!ecore && necore) {
                    int nhead = nrow0 | (63 - __clzll(nst & ((4ull << lane) - 1)));
                    l_union(lp, myhead, nhead);
                }
            }
        }
    }
    __syncthreads();
    // write parent for ALL pixels: core -> global root, non-core -> -1
    #pragma unroll
    for (int pass = 0; pass < 4; ++pass) {
        int li = tid + pass * THREADS;
        int v = -1;
        if (lc8[li] & 2) {
            int root = li, p;
            while ((p = lp[root]) != root) root = p;   // lp stable after barrier
            v = (r0 + (root >> 6)) * WW + c0 + (root & 63);
        }
        int gi = (r0 + (li >> 6)) * WW + c0 + (li & 63);
        parent[gi] = v;
    }
}

// union only tile-crossing edges (16x64 tiles)
__global__ __launch_bounds__(MTHREADS) void k_merge(const uint8_t* __restrict__ flags,
                                                    int* __restrict__ parent) {
    int tile_x = blockIdx.x & 31, tile_y = blockIdx.x >> 5;
    int r0 = tile_y << 4, c0 = tile_x << 6;
    int t = threadIdx.x;
    int lane = t & 63;

    if (t < 64) {                                    // top row, lr=0, lc=t
        int r = r0, c = c0 + t, i = r * WW + c;
        bool selfC = (flags[i] & 2) != 0;
        bool nC = false, nwC = false, neC = false;
        if (selfC && r > 0) {
            nC  = (flags[i - WW] & 2) != 0;
            nwC = (c > 0)      && (flags[i - WW - 1] & 2);
            neC = (c < WW - 1) && (flags[i - WW + 1] & 2);
        }
        int did = 0, ra = -1, rb = -1;
        if (selfC && r > 0 && nC) { ra = uf_find(parent, i); rb = uf_find(parent, i - WW); did = 1; }
        int pra = __shfl_up(ra, 1), prb = __shfl_up(rb, 1), pdid = __shfl_up(did, 1);
        bool head = (lane == 0) || !pdid || pra != ra || prb != rb;
        if (did && head) uf_union(parent, ra, rb);
        if (selfC && r > 0) {
            if (t == 0) {
                if (nwC) uf_union(parent, i, i - WW - 1);          // diag tile
                if (!nC && neC) uf_union(parent, i, i - WW + 1);
            } else if (t == 63) {
                if (!nC && nwC) uf_union(parent, i, i - WW - 1);
                if (neC) {
                    bool eC = (c < WW - 1) && (flags[i + 1] & 2);
                    if (!eC) uf_union(parent, i, i - WW + 1);
                }
            } else if (!nC) {
                if (nwC) uf_union(parent, i, i - WW - 1);
                if (neC) uf_union(parent, i, i - WW + 1);
            }
        }
        if (t == 0 && selfC && c > 0 && (flags[i - 1] & 2))        // corner W edge
            uf_union(parent, i, i - 1);
    } else if (t < 64 + TH - 1) {                    // left col, lr=1..15, lc=0
        int lr = t - 63;
        int r = r0 + lr, c = c0, i = r * WW + c;
        bool selfC = (flags[i] & 2) != 0;
        bool wC = false, nwC = false;
        if (selfC && c > 0) {
            wC  = (flags[i - 1] & 2) != 0;
            nwC = (flags[i - WW - 1] & 2) != 0;
        }
        int did = 0, ra = -1, rb = -1;
        if (selfC && wC) { ra = uf_find(parent, i); rb = uf_find(parent, i - 1); did = 1; }
        int pra = __shfl_up(ra, 1), prb = __shfl_up(rb, 1), pdid = __shfl_up(did, 1);
        bool head = (lane == 0) || !pdid || pra != ra || prb != rb;
        if (did && head) uf_union(parent, ra, rb);
        if (selfC && !wC && nwC) uf_union(parent, i, i - WW - 1);
    } else if (t < 64 + 2 * (TH - 1)) {              // right col, lr=1..15, lc=63
        int lr = t - (64 + TH - 2);
        int r = r0 + lr, c = c0 + 63, i = r * WW + c;
        bool selfC = (flags[i] & 2) != 0;
        if (selfC && c < WW - 1) {
            bool neC = (flags[i - WW + 1] & 2) != 0;
            bool eC  = (flags[i + 1] & 2) != 0;
            if (neC && !eC) uf_union(parent, i, i - WW + 1);
        }
    }
}

// ---------------- flatten: parent[i] -> final global root ----------------
__global__ __launch_bounds__(THREADS) void k_flatten(int* __restrict__ parent) {
    int i4 = (blockIdx.x * THREADS + threadIdx.x) * 4;
    vi4 v = *((vi4*)(parent + i4));
    vi4 o = v;
    #pragma unroll
    for (int t = 0; t < 4; ++t) {
        int p = v[t];
        if (p >= 0) {
            int q = uf_load(parent, p);
            while (q != p) { p = q; q = uf_load(parent, p); }
            v[t] = p;
        }
    }
    if (v.x != o.x || v.y != o.y || v.z != o.z || v.w != o.w)
        *((vi4*)(parent + i4)) = v;
}

// ---------------- border + stats: parent[] holds FINAL roots ----------------
// Neighbor probe via 3 coalesced row loads + 6 wave shuffles.
__global__ __launch_bounds__(THREADS) void k_border_stats(
        const uint8_t* __restrict__ flags, const int* __restrict__ parent,
        int* __restrict__ labfull, int* __restrict__ sizes,
        unsigned* __restrict__ colsum,
        int* __restrict__ cand, int* __restrict__ counter) {
    __shared__ int s_lab[HSZ];
    __shared__ int s_sz[HSZ];
    __shared__ unsigned s_cs[HSZ];
    const int tid = threadIdx.x;
    for (int t = tid; t < HSZ; t += THREADS) {
        s_lab[t] = -1; s_sz[t] = 0; s_cs[t] = 0;
    }
    __syncthreads();

    const int i = blockIdx.x * THREADS + tid;
    const int f = flags[i];
    const int r = i >> 11, c = i & (WW - 1);
    const int lane = tid & 63;

    // 3 coalesced row loads; row predicates are wave-uniform (WW % 64 == 0)
    const int pc = parent[i];
    const int pn = (r > 0)      ? parent[i - WW] : -1;
    const int ps = (r < HH - 1) ? parent[i + WW] : -1;

    // lateral neighbors via shuffles; edge lanes fetch directly
    int wv_c = __shfl_up(pc, 1);
    int wv_n = __shfl_up(pn, 1);
    int wv_s = __shfl_up(ps, 1);
    if (lane == 0) {
        bool ok = (c > 0);
        wv_c = ok ? parent[i - 1] : -1;
        wv_n = (ok && r > 0)      ? parent[i - WW - 1] : -1;
        wv_s = (ok && r < HH - 1) ? parent[i + WW - 1] : -1;
    }
    int ev_c = __shfl_down(pc, 1);
    int ev_n = __shfl_down(pn, 1);
    int ev_s = __shfl_down(ps, 1);
    if (lane == 63) {
        bool ok = (c < WW - 1);
        ev_c = ok ? parent[i + 1] : -1;
        ev_n = (ok && r > 0)      ? parent[i - WW + 1] : -1;
        ev_s = (ok && r < HH - 1) ? parent[i + WW + 1] : -1;
    }

    int lab = BIGL;
    if (f & 2) {
        lab = pc;                                // final root
    } else if (f & 1) {                          // active non-core: min core nbr
        int m = BIGL;
        if (pn   >= 0 && pn   < m) m = pn;
        if (ps   >= 0 && ps   < m) m = ps;
        if (wv_c >= 0 && wv_c < m) m = wv_c;
        if (wv_n >= 0 && wv_n < m) m = wv_n;
        if (wv_s >= 0 && wv_s < m) m = wv_s;
        if (ev_c >= 0 && ev_c < m) m = ev_c;
        if (ev_n >= 0 && ev_n < m) m = ev_n;
        if (ev_s >= 0 && ev_s < m) m = ev_s;
        lab = m;                                 // BIGL if no core neighbor
    }
    labfull[i] = lab;

    // wave-level run aggregation (WW % 64 == 0: wave never crosses a row)
    int labp = __shfl_up(lab, 1);
    bool head = (lane == 0) || (labp != lab);
    u64 hm = __ballot(head);
    if (head && lab < BIGL) {
        u64 rest = (hm >> lane) >> 1;
        int len = rest ? __ffsll(rest) : (64 - lane);
        unsigned csum = (unsigned)(c * len + len * (len - 1) / 2);
        unsigned slot = (((unsigned)lab * 2654435761u) >> 20) & (HSZ - 1);
        for (;;) {
            int old = atomicCAS(&s_lab[slot], -1, lab);
            if (old == -1 || old == lab) {
                atomicAdd(&s_sz[slot], len);
                atomicAdd(&s_cs[slot], csum);
                break;
            }
            slot = (slot + 1) & (HSZ - 1);
        }
    }
    __syncthreads();
    for (int t = tid; t < HSZ; t += THREADS) {
        int lb = s_lab[t];
        if (lb >= 0) {
            int add = s_sz[t];
            int old = atomicAdd(&sizes[lb], add);
            if (old < MINCL && old + add >= MINCL) {   // exactly one block sees this
                int p = atomicAdd(counter, 1);
                cand[p] = lb;
            }
            atomicAdd(&colsum[lb], s_cs[t]);
        }
    }
}

// ---- fused single-kernel top-26 selection (NB=128 slices + done-counter) ----
__device__ __forceinline__ u64 wave_min_u64(u64 m) {
    #pragma unroll
    for (int off = 32; off; off >>= 1) {
        u64 o = __shfl_xor(m, off);
        if (o < m) m = o;
    }
    return m;
}

__global__ __launch_bounds__(THREADS) void k_sel(const int* __restrict__ cand,
                                                 int* __restrict__ counter,   // [0]=n, [1]=done
                                                 const int* __restrict__ sizes,
                                                 const unsigned* __restrict__ colsum,
                                                 unsigned long long* __restrict__ top26g,
                                                 signed char* __restrict__ chan) {
    __shared__ u64 wout[4 * NSLOTS];
    const int tid = threadIdx.x, lane = tid & 63, wv = tid >> 6;
    const int n = counter[0];
    int slice = (n + NB - 1) / NB;
    int j0 = blockIdx.x * slice;
    int j1 = j0 + slice; if (j1 > n) j1 = n;
    int len = j1 - j0; if (len < 0) len = 0;
    int chunk = (len + 3) >> 2;
    int s0 = j0 + wv * chunk;
    int s1 = s0 + chunk; if (s1 > j1) s1 = j1;

    u64 kk[3] = { ~0ull, ~0ull, ~0ull };
    #pragma unroll
    for (int t = 0; t < 3; ++t) {
        int j = s0 + lane + 64 * t;
        if (j < s1) {
            int lab = cand[j];
            float mean = (float)colsum[lab] / (float)sizes[lab];
            kk[t] = ((u64)__float_as_uint(mean) << 32) | (unsigned)lab;
        }
    }
    for (int k = 0; k < NSLOTS; ++k) {
        u64 m = kk[0]; int li = 0;
        if (kk[1] < m) { m = kk[1]; li = 1; }
        if (kk[2] < m) { m = kk[2]; li = 2; }
        u64 mpre = m;
        m = wave_min_u64(m);
        if (mpre == m && m != ~0ull) kk[li] = ~0ull;
        if (lane == 0) wout[wv * NSLOTS + k] = m;
    }
    __syncthreads();
    if (wv == 0) {
        u64 a = (lane < 4 * NSLOTS) ? wout[lane] : ~0ull;
        u64 b = (lane + 64 < 4 * NSLOTS) ? wout[lane + 64] : ~0ull;
        for (int k = 0; k < NSLOTS; ++k) {
            u64 m = a < b ? a : b; int li = a < b ? 0 : 1;
            u64 mpre = m;
            m = wave_min_u64(m);
            if (mpre == m && m != ~0ull) { if (li == 0) a = ~0ull; else b = ~0ull; }
            if (lane == 0) top26g[blockIdx.x * NSLOTS + k] = m;
        }
    }
    __syncthreads();
    __shared__ int lastflag;
    if (tid == 0) {
        __threadfence();
        lastflag = (atomicAdd(&counter[1], 1) == NB - 1);
    }
    __syncthreads();
    if (!lastflag) return;

    u64 mk[13];
    #pragma unroll
    for (int t = 0; t < 13; ++t) {
        int j = wv * 832 + lane + 64 * t;
        mk[t] = __hip_atomic_load(&top26g[j], __ATOMIC_RELAXED, __HIP_MEMORY_SCOPE_AGENT);
    }
    for (int k = 0; k < NSLOTS; ++k) {
        u64 m = mk[0]; int li = 0;
        #pragma unroll
        for (int t = 1; t < 13; ++t) if (mk[t] < m) { m = mk[t]; li = t; }
        u64 mpre = m;
        m = wave_min_u64(m);
        if (mpre == m && m != ~0ull) mk[li] = ~0ull;
        if (lane == 0) wout[wv * NSLOTS + k] = m;
    }
    __syncthreads();
    if (wv == 0) {
        u64 a = (lane < 4 * NSLOTS) ? wout[lane] : ~0ull;
        u64 b = (lane + 64 < 4 * NSLOTS) ? wout[lane + 64] : ~0ull;
        for (int k = 0; k < NSLOTS; ++k) {
            u64 m = a < b ? a : b; int li = a < b ? 0 : 1;
            u64 mpre = m;
            m = wave_min_u64(m);
            if (mpre == m && m != ~0ull) { if (li == 0) a = ~0ull; else b = ~0ull; }
            if (lane == 0 && m != ~0ull)
                chan[(unsigned int)(m & 0xFFFFFFFFull)] = (signed char)k;
        }
    }
}

// sparse one-hot output: out[] pre-zeroed by k_local; write only the 1s.
__global__ __launch_bounds__(THREADS) void k_output(const int* __restrict__ labfull,
                                                    const signed char* __restrict__ chan,
                                                    int* __restrict__ out) {
    int i4 = (blockIdx.x * THREADS + threadIdx.x) * 4;
    vi4 lv = __builtin_nontemporal_load((const vi4*)(labfull + i4));
    #pragma unroll
    for (int t = 0; t < 4; ++t) {
        int lab = lv[t];
        if (lab < BIGL) {
            int ch = chan[lab];
            if (ch >= 0)
                __builtin_nontemporal_store(1, out + (size_t)ch * HWN + i4 + t);
        }
    }
}

extern "C" void kernel_launch(void* const* d_in, const int* in_sizes, int n_in,
                              void* d_out, int out_size, void* d_ws, size_t ws_size,
                              hipStream_t stream) {
    const float* mask = (const float*)d_in[0];
    int* out = (int*)d_out;

    char* w = (char*)d_ws;
    int* parent                 = (int*)(w);                          //  8 MB
    int* labfull                = (int*)(w + (size_t)HWN * 4);        //  8 MB
    int* sizes                  = (int*)(w + (size_t)HWN * 8);        //  8 MB
    unsigned* colsum            = (unsigned*)(w + (size_t)HWN * 12);  //  8 MB (u32)
    uint8_t* flags              = (uint8_t*)(w + (size_t)HWN * 16);   //  2 MB
    signed char* chan           = (signed char*)(w + (size_t)HWN * 17); // 2 MB
    int* cand                   = (int*)(w + (size_t)HWN * 18);       // 280 KB
    int* counter                = (int*)(w + (size_t)HWN * 18 + MAXCAND * 4);  // [0]=n,[1]=done
    unsigned long long* top26g  = (unsigned long long*)(w + (size_t)HWN * 18 + MAXCAND * 4 + 256);

    // no memsets: k_local zeros sizes/colsum/chan/counter and the out buffer
    k_local       <<<NTIL, THREADS, 0, stream>>>(mask, flags, parent,
                                                 sizes, colsum, chan, counter, out);
    k_merge       <<<NTIL, MTHREADS, 0, stream>>>(flags, parent);
    k_flatten     <<<HWN / (4 * THREADS), THREADS, 0, stream>>>(parent);
    k_border_stats<<<NBORDER, THREADS, 0, stream>>>(flags, parent, labfull, sizes,
                                                    colsum, cand, counter);
    k_sel         <<<NB, THREADS, 0, stream>>>(cand, counter, sizes, colsum, top26g, chan);
    k_output      <<<HWN / (4 * THREADS), THREADS, 0, stream>>>(labfull, chan, out);
}